// Round 4
// baseline (121.476 us; speedup 1.0000x reference)
//
#include <hip/hip_runtime.h>

// Problem constants (from reference)
constexpr int BATCH = 16384;
constexpr int NN    = 4096;    // NUM_NEURONS
constexpr int BS    = 32;      // BLOCK_SIZE
constexpr int NB    = NN / BS; // 128 blocks

constexpr int THREADS     = 256;            // 4 waves
constexpr int SLABS       = 4;              // row-slabs per lane per iteration
constexpr int ROWS_PER_WG = 512;
constexpr int ROWS_PER_IT = 32 * SLABS;     // 4 waves x 8 rows x 4 slabs = 128
constexpr int ITERS       = ROWS_PER_WG / ROWS_PER_IT; // 4

typedef float f32x4 __attribute__((ext_vector_type(4)));
typedef float f32x2 __attribute__((ext_vector_type(2)));

// Lane layout within a wave: r = lane>>3 (row in 8-row slab), g = lane&7
// (column float4-quad). Each dwordx4 global access covers 8 full 128-B lines.
// Each lane owns SLABS=4 rows (stride 32) x 4 output columns.
//
// Per k-step: ONE ds_read_b128 of A[k][4g..4g+3] (8 distinct addrs spanning
// all 32 banks, broadcast over r -> conflict-free) feeds 16 FMAs (4 slabs x
// 4 cols). v[row_i,k] broadcast from lane (r, k>>2) component (k&3) via
// ds_swizzle (BitMode: and=0x18 keeps row bits, or=(k>>2) selects source).
template <int K>
struct KStep {
    static __device__ __forceinline__ void run(const f32x4* __restrict__ w,
                                               const f32x4* __restrict__ Alds,
                                               int g, float (*__restrict__ acc)[4]) {
        constexpr int s = K >> 2;   // source lane within 8-lane group
        constexpr int e = K & 3;    // component of that lane's float4
        const f32x4 a = Alds[K * 8 + g];
#pragma unroll
        for (int i = 0; i < SLABS; ++i) {
            const float vk = __int_as_float(
                __builtin_amdgcn_ds_swizzle(__float_as_int(w[i][e]), (s << 5) | 0x18));
            acc[i][0] = fmaf(vk, a.x, acc[i][0]);
            acc[i][1] = fmaf(vk, a.y, acc[i][1]);
            acc[i][2] = fmaf(vk, a.z, acc[i][2]);
            acc[i][3] = fmaf(vk, a.w, acc[i][3]);
        }
        KStep<K + 1>::run(w, Alds, g, acc);
    }
};
template <>
struct KStep<BS> {
    static __device__ __forceinline__ void run(const f32x4* __restrict__,
                                               const f32x4* __restrict__,
                                               int, float (*__restrict__)[4]) {}
};

__global__ __launch_bounds__(THREADS) void tn_kernel(
    const float* __restrict__ v,
    const float* __restrict__ dx,
    const float* __restrict__ A,
    const float* __restrict__ Bm,
    const float* __restrict__ bsc,
    float* __restrict__ out)
{
    __shared__ f32x4 Alds[BS * BS / 4]; // A[k][l], l fastest (256 x float4)

    const int tid  = threadIdx.x;
    const int nblk = blockIdx.x & (NB - 1);
    const int rt   = blockIdx.x >> 7;

    // Stage A[nblk] (4 KB): 256 threads x one float4
    Alds[tid] = reinterpret_cast<const f32x4*>(A + nblk * (BS * BS))[tid];
    __syncthreads();

    const float bias = *bsc;
    const int lane = tid & 63;
    const int wv   = tid >> 6;
    const int r    = lane >> 3;
    const int g    = lane & 7;

    // B rows for this lane's 4 output columns (8 contiguous floats, L2-hot).
    const f32x4* Bp = reinterpret_cast<const f32x4*>(Bm + nblk * (BS * 2) + g * 8);
    const f32x4 B0 = Bp[0];  // {B[c0][0],B[c0][1],B[c1][0],B[c1][1]}
    const f32x4 B1 = Bp[1];  // {B[c2][0],B[c2][1],B[c3][0],B[c3][1]}

    int rowb = rt * ROWS_PER_WG + wv * 8 + r;
    size_t off = (size_t)rowb * NN + nblk * BS + g * 4;
    constexpr size_t SLAB_STRIDE = (size_t)32 * NN;   // 32 rows
    constexpr size_t IT_STRIDE   = (size_t)ROWS_PER_IT * NN;

    // Software pipeline: prefetch next iteration's v/dx while computing.
    f32x4 w[SLABS];
    f32x2 dd[SLABS];
#pragma unroll
    for (int i = 0; i < SLABS; ++i) {
        w[i]  = __builtin_nontemporal_load(
                    reinterpret_cast<const f32x4*>(v + off + i * SLAB_STRIDE));
        dd[i] = *reinterpret_cast<const f32x2*>(dx + (size_t)(rowb + i * 32) * 2);
    }

#pragma unroll 1
    for (int it = 0; it < ITERS; ++it) {
        f32x4 wn[SLABS];
        f32x2 ddn[SLABS];
        if (it < ITERS - 1) {
#pragma unroll
            for (int i = 0; i < SLABS; ++i) {
                wn[i]  = __builtin_nontemporal_load(
                             reinterpret_cast<const f32x4*>(v + off + IT_STRIDE + i * SLAB_STRIDE));
                ddn[i] = *reinterpret_cast<const f32x2*>(
                             dx + (size_t)(rowb + ROWS_PER_IT + i * 32) * 2);
            }
        } else {
#pragma unroll
            for (int i = 0; i < SLABS; ++i) { wn[i] = w[i]; ddn[i] = dd[i]; }
        }

        float acc[SLABS][4] = {};
        KStep<0>::run(w, Alds, g, acc);

#pragma unroll
        for (int i = 0; i < SLABS; ++i) {
            f32x4 o;
            o.x = fmaxf(fmaf(dd[i].x, B0.x, fmaf(dd[i].y, B0.y, acc[i][0] + bias)), 0.f);
            o.y = fmaxf(fmaf(dd[i].x, B0.z, fmaf(dd[i].y, B0.w, acc[i][1] + bias)), 0.f);
            o.z = fmaxf(fmaf(dd[i].x, B1.x, fmaf(dd[i].y, B1.y, acc[i][2] + bias)), 0.f);
            o.w = fmaxf(fmaf(dd[i].x, B1.z, fmaf(dd[i].y, B1.w, acc[i][3] + bias)), 0.f);
            __builtin_nontemporal_store(o, reinterpret_cast<f32x4*>(out + off + i * SLAB_STRIDE));
        }

#pragma unroll
        for (int i = 0; i < SLABS; ++i) { w[i] = wn[i]; dd[i] = ddn[i]; }
        rowb += ROWS_PER_IT;
        off  += IT_STRIDE;
    }
}

extern "C" void kernel_launch(void* const* d_in, const int* in_sizes, int n_in,
                              void* d_out, int out_size, void* d_ws, size_t ws_size,
                              hipStream_t stream) {
    const float* v  = (const float*)d_in[0];  // [16384,4096]
    const float* dx = (const float*)d_in[1];  // [16384,2]
    const float* A  = (const float*)d_in[2];  // [128,32,32]
    const float* Bm = (const float*)d_in[3];  // [4096,2]
    const float* b  = (const float*)d_in[4];  // scalar
    float* out = (float*)d_out;               // [16384,4096]

    const int grid = NB * (BATCH / ROWS_PER_WG); // 128 * 32 = 4096
    tn_kernel<<<dim3(grid), dim3(THREADS), 0, stream>>>(v, dx, A, Bm, b, out);
}